// Round 9
// baseline (125.633 us; speedup 1.0000x reference)
//
#include <hip/hip_runtime.h>

// GraphConvBlock, v9 = v8 with node-stage wave tiles 64oc x 128pix, K-split 4.
//  - reads/phase/wave 16 -> 12 (FLOP per LDS byte 32 -> 42.7), MFMA same.
//  - 4-way K-partial reduction via single-round packed-bf16 LDS exchange.
//  - staging reordered (acts before weight gloads) + lgkm-only seal barrier:
//    head no longer drains the async weight pipeline.
// Stem keeps v8 (4wr x 2kh) structure. Layouts/swizzles/setup kernel = v8.

typedef __bf16 bf16x8 __attribute__((ext_vector_type(8)));
typedef float f32x4 __attribute__((ext_vector_type(4)));

union U4 { uint4 u; bf16x8 b; };

__device__ inline unsigned pk_bf16(float lo, float hi) {
  unsigned r;
  asm volatile("v_cvt_pk_bf16_f32 %0, %1, %2" : "=v"(r) : "v"(lo), "v"(hi));
  return r;
}

__device__ inline unsigned addpk(unsigned a, unsigned b) {
  float alo = __builtin_bit_cast(float, a << 16);
  float ahi = __builtin_bit_cast(float, a & 0xFFFF0000u);
  float blo = __builtin_bit_cast(float, b << 16);
  float bhi = __builtin_bit_cast(float, b & 0xFFFF0000u);
  return pk_bf16(alo + blo, ahi + bhi);
}

__device__ inline uint4 addpk4(uint4 a, uint4 b) {
  return make_uint4(addpk(a.x, b.x), addpk(a.y, b.y), addpk(a.z, b.z), addpk(a.w, b.w));
}

__device__ __forceinline__ void gload16(const unsigned* g, unsigned* l) {
  __builtin_amdgcn_global_load_lds(
      (const __attribute__((address_space(1))) unsigned*)(g),
      (__attribute__((address_space(3))) unsigned*)(l), 16, 0, 0);
}

template <int N>
__device__ __forceinline__ void waitcnt_vm_lgkm() {
  if constexpr (N == 0)
    asm volatile("s_waitcnt vmcnt(0) lgkmcnt(0)" ::: "memory");
  else if constexpr (N == 1)
    asm volatile("s_waitcnt vmcnt(1) lgkmcnt(0)" ::: "memory");
  else
    asm volatile("s_waitcnt vmcnt(2) lgkmcnt(0)" ::: "memory");
}

__device__ __forceinline__ void seal_lgkm_barrier() {
  asm volatile("s_waitcnt lgkmcnt(0)" ::: "memory");
  __builtin_amdgcn_s_barrier();
  __builtin_amdgcn_sched_barrier(0);
}

#define WB_WORDS 479232

// ---------------- fused setup kernel (unchanged from v8) ---------------------
__global__ __launch_bounds__(512) void setup_all(
    const float* __restrict__ x, const float* __restrict__ W0,
    const float* __restrict__ Wn, unsigned* __restrict__ B0,
    unsigned* __restrict__ B1, unsigned* __restrict__ B2,
    unsigned* __restrict__ T, unsigned* __restrict__ Wb) {
  __shared__ float xl[2 * 64 * 65];
  const int tid = threadIdx.x;
  const int bid = blockIdx.x;
  const int n = bid & 7;

#pragma unroll
  for (int it = 0; it < 4; ++it) {
    unsigned gid = (unsigned)bid * 512 + tid + it * 131072u;
    if (gid < WB_WORDS) {
      const float* src;
      int CIN, c, r, j;
      if (gid < 36864) {
        src = W0; CIN = 64;
        c = gid >> 11; int w = gid & 2047; r = w >> 5; j = w & 31;
      } else {
        unsigned g2 = gid - 36864;
        int s = g2 / 73728; unsigned r2 = g2 % 73728;
        src = Wn + (size_t)s * 147456; CIN = 128;
        c = r2 >> 12; int w = r2 & 4095; r = w >> 6; j = w & 63;
      }
      int ochalf = c / 9, tap = c % 9;
      int dy = tap / 3, dx = tap % 3;
      int icpair = j ^ ((r & 7) << 2);
      int oc = ochalf * 64 + r;
      size_t base = (((size_t)oc * CIN + 2 * icpair) * 3 + dy) * 3 + dx;
      Wb[gid] = pk_bf16(src[base], src[base + 9]);
    }
  }

  {
    unsigned gid = (unsigned)bid * 512 + tid;
    if (gid < 116480) {
      unsigned* buf; int CW; unsigned u;
      if (gid < 99840) {
        buf = gid < 33280 ? B0 : (gid < 66560 ? B1 : B2);
        u = gid % 33280; CW = 64;
      } else {
        buf = T; u = gid - 99840; CW = 32;
      }
      int per_n = 65 * CW;
      int nn = u / per_n;
      unsigned v = u % per_n;
      int pix = (v * 4) / CW, cw = (v * 4) % CW;
      int row, col;
      if (pix < 66) { row = 0; col = pix; }
      else if (pix < 132) { row = 65; col = pix - 66; }
      else if (pix < 196) { row = pix - 131; col = 0; }
      else { row = pix - 195; col = 65; }
      *(uint4*)&buf[((((size_t)nn * 66 + row) * 66 + col) * CW) + cw] =
          make_uint4(0, 0, 0, 0);
    }
  }

  {
    int hh = bid >> 3;
    int sub = tid >> 8;
    int t8 = tid & 255;
    int h = hh * 2 + sub;
#pragma unroll
    for (int k = 0; k < 16; ++k) {
      int idx = t8 + k * 256;
      int ic = idx >> 6, w = idx & 63;
      xl[(sub * 64 + w) * 65 + ic] = x[(((size_t)n * 64 + ic) * 64 + h) * 64 + w];
    }
    __syncthreads();
#pragma unroll
    for (int k = 0; k < 8; ++k) {
      int idx = t8 + k * 256;
      int w = idx >> 5, icp = idx & 31;
      unsigned v = pk_bf16(xl[(sub * 64 + w) * 65 + icp * 2],
                           xl[(sub * 64 + w) * 65 + icp * 2 + 1]);
      int wp = w + 1;
      int pos = icp ^ ((wp & 7) << 2);
      T[(((size_t)n * 66 + (h + 1)) * 66 + wp) * 32 + pos] = v;
    }
  }
}

// ---------------- stem conv (v8 structure, CIN=64) ----------------------------
__global__ __launch_bounds__(512, 2) void conv_stem(
    const unsigned* __restrict__ in0, const unsigned* __restrict__ wb,
    const float* __restrict__ bias, unsigned* __restrict__ outp) {
  constexpr int WPP = 32, CHW = 2048, WL = 1, ROWW = 66 * 32;
  constexpr int ACTW = 6 * ROWW, ALDS_W = 16384;
  constexpr int R4_U4 = 4 * ROWW / 4, R2_U4 = 2 * ROWW / 4;
  constexpr int AJ4 = (R4_U4 + 511) / 512, LJ = (R2_U4 + 511) / 512;

  __shared__ unsigned Alds[ALDS_W];
  __shared__ unsigned Wlds[3][CHW];

  const int tid = threadIdx.x;
  const int lane = tid & 63;
  const int wav = tid >> 6;
  const int wr = wav >> 1;
  const int kh = wav & 1;
  const int l15 = lane & 15, q = lane >> 4;
  const int bid = blockIdx.x;
  const int n = bid & 7;
  const int ochalf = (bid >> 3) & 1;
  const int h0 = (bid >> 4) * 4;

  const unsigned* wbase = wb + (size_t)ochalf * 9 * CHW;
  const size_t abase = ((size_t)n * 66 + h0) * ROWW;
  const uint4* g0 = (const uint4*)(in0 + abase);

  uint4 l0[LJ];
#pragma unroll
  for (int j = 0; j < LJ; ++j) {
    int i = tid + j * 512;
    if (i < R2_U4) l0[j] = g0[R4_U4 + i];
  }
  // acts rows 0..3 first (older than weight gloads in vmcnt queue)
#pragma unroll
  for (int j = 0; j < AJ4; ++j) {
    int i = tid + j * 512;
    if (i < R4_U4) *(uint4*)&Alds[4 * i] = g0[i];
  }
  // weight chunks 0,1 async
#pragma unroll
  for (int s = 0; s < WL; ++s)
    gload16(wbase + s * 2048 + tid * 4, &Wlds[0][s * 2048 + wav * 256]);
#pragma unroll
  for (int s = 0; s < WL; ++s)
    gload16(wbase + CHW + s * 2048 + tid * 4, &Wlds[1][s * 2048 + wav * 256]);
  seal_lgkm_barrier();  // rows 0..3 sealed; weight loads stay in flight

  f32x4 acc[4][4];
#pragma unroll
  for (int m = 0; m < 4; ++m)
#pragma unroll
    for (int p = 0; p < 4; ++p) acc[m][p] = (f32x4)0.f;

#pragma unroll
  for (int t = 0; t < 9; ++t) {
    if (t < 8) waitcnt_vm_lgkm<WL>();
    else waitcnt_vm_lgkm<0>();
    __builtin_amdgcn_s_barrier();
    __builtin_amdgcn_sched_barrier(0);

    const unsigned* WB = Wlds[t % 3];
    const int dy = t / 3, dx = t % 3;
    const int arow = (wr + dy) * 66;
    const int kc = kh;  // KCW=1

    __builtin_amdgcn_s_setprio(1);
    bf16x8 a[4];
#pragma unroll
    for (int m = 0; m < 4; ++m) {
      int r = m * 16 + l15;
      U4 u;
      u.u = *(const uint4*)&WB[r * WPP + ((kc * 16 + q * 4) ^ ((r & 7) << 2))];
      a[m] = u.b;
    }
#pragma unroll
    for (int p = 0; p < 4; ++p) {
      int col = p * 16 + l15 + dx;
      U4 u;
      u.u = *(const uint4*)&Alds[(arow + col) * WPP +
                                 ((kc * 16 + q * 4) ^ ((col & 7) << 2))];
      bf16x8 b = u.b;
#pragma unroll
      for (int m = 0; m < 4; ++m)
        acc[m][p] = __builtin_amdgcn_mfma_f32_16x16x32_bf16(a[m], b, acc[m][p], 0, 0, 0);
    }
    __builtin_amdgcn_s_setprio(0);
    __builtin_amdgcn_sched_barrier(0);

    if (t == 0) {
#pragma unroll
      for (int j = 0; j < LJ; ++j) {
        int i = tid + j * 512;
        if (i < R2_U4) *(uint4*)&Alds[4 * (R4_U4 + i)] = l0[j];
      }
    }
    if (t + 2 < 9) {
#pragma unroll
      for (int s = 0; s < WL; ++s)
        gload16(wbase + (size_t)(t + 2) * CHW + s * 2048 + tid * 4,
                &Wlds[(t + 2) % 3][s * 2048 + wav * 256]);
    }
    __builtin_amdgcn_sched_barrier(0);
  }

  __syncthreads();
  float* R = (float*)Alds;
  if (kh) {
#pragma unroll
    for (int m = 0; m < 4; ++m)
#pragma unroll
      for (int p = 0; p < 4; ++p)
        *(f32x4*)&R[(wr * 16 + m * 4 + p) * 256 + lane * 4] = acc[m][p];
  }
  __syncthreads();
  if (kh) return;
#pragma unroll
  for (int m = 0; m < 4; ++m)
#pragma unroll
    for (int p = 0; p < 4; ++p)
      acc[m][p] += *(const f32x4*)&R[(wr * 16 + m * 4 + p) * 256 + lane * 4];

  const int obase = ochalf * 64;
#pragma unroll
  for (int m = 0; m < 4; ++m) {
    int oc0 = obase + m * 16 + q * 4;
    float4 bb = *(const float4*)&bias[oc0];
    int icp0 = oc0 >> 1;
#pragma unroll
    for (int p = 0; p < 4; ++p) {
      int w = p * 16 + l15;
      int wp = w + 1;
      unsigned lo = pk_bf16(acc[m][p][0] + bb.x, acc[m][p][1] + bb.y);
      unsigned hi = pk_bf16(acc[m][p][2] + bb.z, acc[m][p][3] + bb.w);
      int pos = icp0 ^ ((wp & 7) << 2);
      size_t base = (((size_t)n * 66 + (h0 + 1 + wr)) * 66 + wp) * 64;
      *(uint2*)&outp[base + pos] = make_uint2(lo, hi);
    }
  }
}

// ---------------- node conv (CIN=128): wave 64oc x 128pix, K-split 4 ---------
// 8 waves = 2 wp (pixel half: rows {2wp,2wp+1}) x 4 kh (K quarter).
// Reduction: single-round packed-bf16 LDS exchange (groups g=(kh-1)*2+wp).
template <bool DUAL, bool OUTF32>
__global__ __launch_bounds__(512, 2) void conv_node(
    const unsigned* __restrict__ in0, const unsigned* __restrict__ in1,
    const unsigned* __restrict__ wb, const float* __restrict__ bias,
    float bmult, void* __restrict__ outp) {
  constexpr int WPP = 64, CHW = 4096, WL = 2, ROWW = 66 * 64;
  constexpr int ACTW = 6 * ROWW;           // 25344 words (also reduction buf)
  constexpr int R4_U4 = 4 * ROWW / 4, R2_U4 = 2 * ROWW / 4;
  constexpr int AJ4 = (R4_U4 + 511) / 512, LJ = (R2_U4 + 511) / 512;

  __shared__ unsigned Alds[ACTW];
  __shared__ unsigned Wlds[3][CHW];

  const int tid = threadIdx.x;
  const int lane = tid & 63;
  const int wav = tid >> 6;
  const int wp = wav & 1;                  // pixel half
  const int kh = wav >> 1;                 // K quarter 0..3
  const int l15 = lane & 15, q = lane >> 4;
  const int bid = blockIdx.x;
  const int n = bid & 7;
  const int ochalf = (bid >> 3) & 1;
  const int h0 = (bid >> 4) * 4;

  const unsigned* wbase = wb + (size_t)ochalf * 9 * CHW;
  const size_t abase = ((size_t)n * 66 + h0) * ROWW;
  const uint4* g0 = (const uint4*)(in0 + abase);
  const uint4* g1 = (const uint4*)(in1 + abase);

  uint4 l0[LJ], l1[LJ];
#pragma unroll
  for (int j = 0; j < LJ; ++j) {
    int i = tid + j * 512;
    if (i < R2_U4) {
      l0[j] = g0[R4_U4 + i];
      if (DUAL) l1[j] = g1[R4_U4 + i];
    }
  }
  // acts rows 0..3 first (older than weight gloads)
#pragma unroll
  for (int j = 0; j < AJ4; ++j) {
    int i = tid + j * 512;
    if (i < R4_U4) {
      uint4 v = g0[i];
      if (DUAL) v = addpk4(v, g1[i]);
      *(uint4*)&Alds[4 * i] = v;
    }
  }
#pragma unroll
  for (int s = 0; s < WL; ++s)
    gload16(wbase + s * 2048 + tid * 4, &Wlds[0][s * 2048 + wav * 256]);
#pragma unroll
  for (int s = 0; s < WL; ++s)
    gload16(wbase + CHW + s * 2048 + tid * 4, &Wlds[1][s * 2048 + wav * 256]);
  seal_lgkm_barrier();

  f32x4 acc[4][8];
#pragma unroll
  for (int m = 0; m < 4; ++m)
#pragma unroll
    for (int p = 0; p < 8; ++p) acc[m][p] = (f32x4)0.f;

  const int kq = kh * 16 + q * 4;          // K-word base for this wave

#pragma unroll
  for (int t = 0; t < 9; ++t) {
    if (t < 8) waitcnt_vm_lgkm<WL>();
    else waitcnt_vm_lgkm<0>();
    __builtin_amdgcn_s_barrier();
    __builtin_amdgcn_sched_barrier(0);

    const unsigned* WB = Wlds[t % 3];
    const int dy = t / 3, dx = t % 3;

    __builtin_amdgcn_s_setprio(1);
    bf16x8 a[4];
#pragma unroll
    for (int m = 0; m < 4; ++m) {
      int r = m * 16 + l15;
      U4 u;
      u.u = *(const uint4*)&WB[r * WPP + (kq ^ ((r & 7) << 2))];
      a[m] = u.b;
    }
#pragma unroll
    for (int p = 0; p < 8; ++p) {
      int row_in = 2 * wp + (p >> 2) + dy;
      int col = (p & 3) * 16 + l15 + dx;
      U4 u;
      u.u = *(const uint4*)&Alds[(row_in * 66 + col) * WPP +
                                 (kq ^ ((col & 7) << 2))];
      bf16x8 b = u.b;
#pragma unroll
      for (int m = 0; m < 4; ++m)
        acc[m][p] = __builtin_amdgcn_mfma_f32_16x16x32_bf16(a[m], b, acc[m][p], 0, 0, 0);
    }
    __builtin_amdgcn_s_setprio(0);
    __builtin_amdgcn_sched_barrier(0);

    if (t == 0) {
#pragma unroll
      for (int j = 0; j < LJ; ++j) {
        int i = tid + j * 512;
        if (i < R2_U4) {
          uint4 v = l0[j];
          if (DUAL) v = addpk4(v, l1[j]);
          *(uint4*)&Alds[4 * (R4_U4 + i)] = v;
        }
      }
    }
    if (t + 2 < 9) {
#pragma unroll
      for (int s = 0; s < WL; ++s)
        gload16(wbase + (size_t)(t + 2) * CHW + s * 2048 + tid * 4,
                &Wlds[(t + 2) % 3][s * 2048 + wav * 256]);
    }
    __builtin_amdgcn_sched_barrier(0);
  }

  // ---- 4-way K reduction: packed-bf16 single-round exchange ----
  __syncthreads();
  if (kh != 0) {
    unsigned* Rb = &Alds[((kh - 1) * 2 + wp) * 4096];
#pragma unroll
    for (int m = 0; m < 4; ++m)
#pragma unroll
      for (int p = 0; p < 8; ++p) {
        unsigned u0 = pk_bf16(acc[m][p][0], acc[m][p][1]);
        unsigned u1 = pk_bf16(acc[m][p][2], acc[m][p][3]);
        *(uint2*)&Rb[(m * 8 + p) * 128 + lane * 2] = make_uint2(u0, u1);
      }
  }
  __syncthreads();
  if (kh != 0) return;

#pragma unroll
  for (int gi = 0; gi < 3; ++gi) {
    const unsigned* Rb = &Alds[(gi * 2 + wp) * 4096];
#pragma unroll
    for (int m = 0; m < 4; ++m)
#pragma unroll
      for (int p = 0; p < 8; ++p) {
        uint2 v = *(const uint2*)&Rb[(m * 8 + p) * 128 + lane * 2];
        acc[m][p][0] += __builtin_bit_cast(float, v.x << 16);
        acc[m][p][1] += __builtin_bit_cast(float, v.x & 0xFFFF0000u);
        acc[m][p][2] += __builtin_bit_cast(float, v.y << 16);
        acc[m][p][3] += __builtin_bit_cast(float, v.y & 0xFFFF0000u);
      }
  }

  // ---- epilogue (kh==0 waves: wave wp owns rows {h0+2wp, h0+2wp+1}) ----
  const int obase = ochalf * 64;
  if (OUTF32) {
    float* out = (float*)outp;
#pragma unroll
    for (int m = 0; m < 4; ++m) {
      int oc0 = obase + m * 16 + q * 4;
      float4 bb = *(const float4*)&bias[oc0];
#pragma unroll
      for (int p = 0; p < 8; ++p) {
        int row = h0 + 2 * wp + (p >> 2);
        int wcol = (p & 3) * 16 + l15;
#pragma unroll
        for (int j = 0; j < 4; ++j)
          out[(((size_t)n * 128 + oc0 + j) * 64 + row) * 64 + wcol] =
              acc[m][p][j] + ((const float*)&bb)[j] * bmult;
      }
    }
  } else {
    unsigned* out = (unsigned*)outp;
#pragma unroll
    for (int m = 0; m < 4; ++m) {
      int oc0 = obase + m * 16 + q * 4;
      float4 bb = *(const float4*)&bias[oc0];
      int icp0 = oc0 >> 1;
#pragma unroll
      for (int p = 0; p < 8; ++p) {
        int row_out = h0 + 1 + 2 * wp + (p >> 2);
        int wpad = (p & 3) * 16 + l15 + 1;
        unsigned lo = pk_bf16(acc[m][p][0] + bb.x * bmult, acc[m][p][1] + bb.y * bmult);
        unsigned hi = pk_bf16(acc[m][p][2] + bb.z * bmult, acc[m][p][3] + bb.w * bmult);
        int pos = icp0 ^ ((wpad & 7) << 2);
        size_t base = (((size_t)n * 66 + row_out) * 66 + wpad) * 64;
        *(uint2*)&out[base + pos] = make_uint2(lo, hi);
      }
    }
  }
}

// ---------------- launch ------------------------------------------------------
extern "C" void kernel_launch(void* const* d_in, const int* in_sizes, int n_in,
                              void* d_out, int out_size, void* d_ws,
                              size_t ws_size, hipStream_t stream) {
  const float* x = (const float*)d_in[0];
  const float* W0 = (const float*)d_in[1];
  const float* b0 = (const float*)d_in[2];
  const float* Wn = (const float*)d_in[3];
  const float* bn = (const float*)d_in[4];

  const size_t ACTB = (size_t)8 * 66 * 66 * 64;
  const size_t TW = (size_t)8 * 66 * 66 * 32;
  unsigned* B0 = (unsigned*)d_ws;
  unsigned* B1 = B0 + ACTB;
  unsigned* B2 = B1 + ACTB;
  unsigned* T = B2 + ACTB;
  unsigned* Wb = T + TW;

  setup_all<<<256, 512, 0, stream>>>(x, W0, Wn, B0, B1, B2, T, Wb);

  dim3 grid(256), blk(512);
  const unsigned* Wnode = Wb + 36864;
  const size_t NW = 73728;

  conv_stem<<<grid, blk, 0, stream>>>(T, Wb, b0, B0);
  conv_node<false, false><<<grid, blk, 0, stream>>>(B0, B0, Wnode, bn + 0, 1.f, B1);
  conv_node<true, false><<<grid, blk, 0, stream>>>(B0, B1, Wnode + 1 * NW, bn + 128, 2.f, B2);
  conv_node<true, false><<<grid, blk, 0, stream>>>(B1, B2, Wnode + 2 * NW, bn + 256, 2.f, B0);
  conv_node<true, false><<<grid, blk, 0, stream>>>(B2, B0, Wnode + 3 * NW, bn + 384, 2.f, B1);
  conv_node<true, false><<<grid, blk, 0, stream>>>(B0, B1, Wnode + 4 * NW, bn + 512, 2.f, B2);
  conv_node<true, true><<<grid, blk, 0, stream>>>(B1, B2, Wnode + 5 * NW, bn + 640, 2.f, d_out);

  (void)in_sizes; (void)n_in; (void)out_size; (void)ws_size;
}